// Round 14
// baseline (14145.953 us; speedup 1.0000x reference)
//
#include <hip/hip_runtime.h>
#include <hip/hip_bf16.h>

#define HIDN 512
#define EMBD 128
#define NB   1024
#define SL   48
#define NG   2048
#define KA   1152   // A2 row = [xt(128) | ctx(512) | h(512)]
#define CTXO 128
#define HOFF 640

// d_out is FLOAT32: [ output (B,L,H) | h_final (1,B,H) | c_final (1,B,H) ]
#define HPOS ((size_t)25165824)
#define CPOS ((size_t)25690112)

__device__ __forceinline__ float sigmf(float x) { return 1.0f / (1.0f + expf(-x)); }

// ---- W1[n][k] = k<640 ? W_ih[n][k] : W_hh[n][k-640]; b1 = b_ih + b_hh -------------------
__global__ __launch_bounds__(256) void prep_cat(const float* __restrict__ Wih,
                                                const float* __restrict__ Whh,
                                                const float* __restrict__ bih,
                                                const float* __restrict__ bhh,
                                                float* __restrict__ W1,
                                                float* __restrict__ b1) {
  int idx = blockIdx.x * 256 + threadIdx.x;
  if (idx < NG * KA) {
    int n = idx / KA, k = idx - n * KA;
    W1[idx] = (k < 640) ? Wih[(size_t)n * 640 + k] : Whh[(size_t)n * 512 + (k - 640)];
    if (k == 0) b1[n] = bih[n] + bhh[n];
  }
}

__global__ __launch_bounds__(256) void init2(const float* __restrict__ h0,
                                             const float* __restrict__ c0,
                                             float* __restrict__ A2,
                                             float* __restrict__ C) {
  int idx = blockIdx.x * 256 + threadIdx.x;
  int b = idx >> 9, k = idx & 511;
  A2[(size_t)b * KA + CTXO + k] = 0.0f;
  A2[(size_t)b * KA + HOFF + k] = h0[idx];
  C[idx] = c0[idx];
}

__global__ __launch_bounds__(256) void embed2(const int* __restrict__ seq,
                                              const float* __restrict__ emb,
                                              float* __restrict__ A2, int t) {
  int idx = blockIdx.x * 256 + threadIdx.x;
  int b = idx >> 7, k = idx & 127;
  int tok = seq[b * SL + t];
  A2[(size_t)b * KA + k] = emb[(size_t)tok * EMBD + k];
}

template <bool BO, bool HB>
__global__ __launch_bounds__(256) void gemm32(const float* __restrict__ A, int lda,
                                              const float* __restrict__ B, int ldb,
                                              const float* __restrict__ bias,
                                              void* __restrict__ C, int ldc,
                                              int M, int N, int K) {
  __shared__ float As[32][33];
  __shared__ float Bs[32][33];
  const int tx = threadIdx.x & 15, ty = threadIdx.x >> 4;
  const int m0 = blockIdx.y * 32, n0 = blockIdx.x * 32;
  float a00 = 0.f, a01 = 0.f, a10 = 0.f, a11 = 0.f;

  for (int kt = 0; kt < K; kt += 32) {
    const int base = threadIdx.x * 4;
    #pragma unroll
    for (int q = 0; q < 4; ++q) {
      int idx = base + q, r = idx >> 5, cc = idx & 31;
      As[r][cc] = A[(size_t)(m0 + r) * lda + kt + cc];
      Bs[r][cc] = B[(size_t)(n0 + r) * ldb + kt + cc];
    }
    __syncthreads();
    #pragma unroll
    for (int k = 0; k < 32; ++k) {
      float x0 = As[ty * 2][k], x1 = As[ty * 2 + 1][k];
      float y0 = Bs[tx * 2][k], y1 = Bs[tx * 2 + 1][k];
      a00 += x0 * y0; a01 += x0 * y1; a10 += x1 * y0; a11 += x1 * y1;
    }
    __syncthreads();
  }

  const int gm = m0 + ty * 2, gn = n0 + tx * 2;
  if (HB) { float b0 = bias[gn], b1v = bias[gn + 1]; a00 += b0; a01 += b1v; a10 += b0; a11 += b1v; }
  if (BO) {
    __hip_bfloat16* Cb = (__hip_bfloat16*)C;
    Cb[(size_t)gm * ldc + gn]           = __float2bfloat16(a00);
    Cb[(size_t)gm * ldc + gn + 1]       = __float2bfloat16(a01);
    Cb[(size_t)(gm + 1) * ldc + gn]     = __float2bfloat16(a10);
    Cb[(size_t)(gm + 1) * ldc + gn + 1] = __float2bfloat16(a11);
  } else {
    float* Cf = (float*)C;
    Cf[(size_t)gm * ldc + gn]           = a00;
    Cf[(size_t)gm * ldc + gn + 1]       = a01;
    Cf[(size_t)(gm + 1) * ldc + gn]     = a10;
    Cf[(size_t)(gm + 1) * ldc + gn + 1] = a11;
  }
}

// ---- LSTM cell; output (B,L,H) in FLOAT32 -----------------------------------------------
__global__ __launch_bounds__(256) void cell2(const float* __restrict__ gates,
                                             float* __restrict__ C,
                                             float* __restrict__ A2,
                                             float* __restrict__ hcat,
                                             float* __restrict__ outp,
                                             const int* __restrict__ lens, int t) {
  int idx = blockIdx.x * 256 + threadIdx.x;
  int b = idx >> 9, j = idx & 511;
  size_t gb = (size_t)b * NG;
  float gi = gates[gb + j], gf = gates[gb + 512 + j];
  float gg = gates[gb + 1024 + j], go = gates[gb + 1536 + j];
  float co = C[idx];
  float cn = sigmf(gf) * co + sigmf(gi) * tanhf(gg);
  float hn = sigmf(go) * tanhf(cn);
  hcat[(size_t)b * 1024 + j] = hn;
  hcat[(size_t)b * 1024 + 512 + j] = cn;
  bool am = t < lens[b];
  if (am) {
    A2[(size_t)b * KA + HOFF + j] = hn;
    C[idx] = cn;
  }
  outp[((size_t)b * SL + t) * HIDN + j] = am ? hn : 0.0f;
}

__global__ __launch_bounds__(256) void attn_row(const float* __restrict__ dec,
                                                const __hip_bfloat16* __restrict__ ef,
                                                const float* __restrict__ attn,
                                                const float* __restrict__ mask,
                                                const int* __restrict__ lens,
                                                float* __restrict__ A2,
                                                const float* __restrict__ v, int t) {
  __shared__ float sdec[HIDN];
  __shared__ float sv[HIDN];
  __shared__ float sa[SL];
  const int b = blockIdx.x;
  for (int k = threadIdx.x; k < HIDN; k += 256) {
    sdec[k] = dec[(size_t)b * HIDN + k];
    sv[k] = v[k];
  }
  __syncthreads();
  if (threadIdx.x < 64) {
    const int tt = threadIdx.x;
    float s = -1e30f;
    if (tt < SL) {
      s = 0.f;
      const __hip_bfloat16* er = ef + ((size_t)b * SL + tt) * HIDN;
      for (int k = 0; k < HIDN; ++k)
        s += sv[k] * tanhf(__bfloat162float(er[k]) + sdec[k]);
    }
    float mx = s;
    #pragma unroll
    for (int off = 32; off >= 1; off >>= 1) mx = fmaxf(mx, __shfl_xor(mx, off, 64));
    float e = (tt < SL) ? expf(s - mx) * mask[b * SL + tt] : 0.f;
    float sum = e;
    #pragma unroll
    for (int off = 32; off >= 1; off >>= 1) sum += __shfl_xor(sum, off, 64);
    if (tt < SL) sa[tt] = e / sum;
  }
  __syncthreads();
  if (t < lens[b]) {
    for (int j = threadIdx.x; j < HIDN; j += 256) {
      float cx = 0.f;
      for (int tt = 0; tt < SL; ++tt)
        cx += sa[tt] * attn[((size_t)b * SL + tt) * HIDN + j];
      A2[(size_t)b * KA + CTXO + j] = cx;
    }
  }
}

// ---- final h, c in FLOAT32 --------------------------------------------------------------
__global__ __launch_bounds__(256) void fin2(const float* __restrict__ A2,
                                            const float* __restrict__ C,
                                            float* __restrict__ outp) {
  int idx = blockIdx.x * 256 + threadIdx.x;
  int b = idx >> 9, k = idx & 511;
  outp[HPOS + idx] = A2[(size_t)b * KA + HOFF + k];
  outp[CPOS + idx] = C[idx];
}

extern "C" void kernel_launch(void* const* d_in, const int* in_sizes, int n_in,
                              void* d_out, int out_size, void* d_ws, size_t ws_size,
                              hipStream_t stream) {
  (void)in_sizes; (void)n_in; (void)out_size; (void)ws_size;
  const int*   seq  = (const int*)d_in[0];
  const int*   lens = (const int*)d_in[1];
  const float* h0   = (const float*)d_in[2];
  const float* c0   = (const float*)d_in[3];
  const float* attn = (const float*)d_in[4];
  const float* mask = (const float*)d_in[5];
  const float* emb  = (const float*)d_in[6];
  const float* W_ih = (const float*)d_in[7];
  const float* W_hh = (const float*)d_in[8];
  const float* b_ih = (const float*)d_in[9];
  const float* b_hh = (const float*)d_in[10];
  const float* Wh   = (const float*)d_in[11];
  const float* Wdp  = (const float*)d_in[12];
  const float* bdp  = (const float*)d_in[13];
  const float* vv   = (const float*)d_in[14];
  float* outp = (float*)d_out;   // FLOAT32 output buffer

  float* ws = (float*)d_ws;
  float* W1    = ws;                                     // 2359296
  float* b1    = ws + 2359296;                           // 2048
  __hip_bfloat16* ef = (__hip_bfloat16*)(ws + 2361344);  // 12582912 f-eq
  float* A2    = ws + 14944256;                          // 1179648
  float* C     = ws + 16123904;                          // 524288
  float* gates = ws + 16648192;                          // 2097152
  float* hcat  = ws + 18745344;                          // 1048576
  float* dec   = ws + 19793920;                          // 524288

  prep_cat<<<(NG * KA + 255) / 256, 256, 0, stream>>>(W_ih, W_hh, b_ih, b_hh, W1, b1);
  gemm32<true, false><<<dim3(HIDN / 32, (NB * SL) / 32), 256, 0, stream>>>(
      attn, HIDN, Wh, HIDN, nullptr, ef, HIDN, NB * SL, HIDN, HIDN);
  init2<<<(NB * HIDN) / 256, 256, 0, stream>>>(h0, c0, A2, C);

  for (int t = 0; t < SL; ++t) {
    embed2<<<(NB * EMBD) / 256, 256, 0, stream>>>(seq, emb, A2, t);
    gemm32<false, true><<<dim3(NG / 32, NB / 32), 256, 0, stream>>>(
        A2, KA, W1, KA, b1, gates, NG, NB, NG, KA);
    cell2<<<(NB * HIDN) / 256, 256, 0, stream>>>(gates, C, A2, hcat, outp, lens, t);
    gemm32<false, true><<<dim3(HIDN / 32, NB / 32), 256, 0, stream>>>(
        hcat, 1024, Wdp, 1024, bdp, dec, HIDN, NB, HIDN, 1024);
    attn_row<<<NB, 256, 0, stream>>>(dec, ef, attn, mask, lens, A2, vv, t);
  }
  fin2<<<(NB * HIDN) / 256, 256, 0, stream>>>(A2, C, outp);
}

// Round 15
// 5926.041 us; speedup vs baseline: 2.3871x; 2.3871x over previous
//
#include <hip/hip_runtime.h>
#include <hip/hip_bf16.h>

#define HIDN 512
#define EMBD 128
#define NB   1024
#define SL   48
#define NG   2048
#define KA   1152   // A2 row = [xt(128) | ctx(512) | h(512)]
#define CTXO 128
#define HOFF 640

// d_out FLOAT32: [ output (B,L,H) | h_final (1,B,H) | c_final (1,B,H) ]
#define HPOS ((size_t)25165824)
#define CPOS ((size_t)25690112)

typedef __attribute__((ext_vector_type(8))) short short8v;
typedef __attribute__((ext_vector_type(4))) float f32x4;

__device__ __forceinline__ float sigmf(float x) { return 1.0f / (1.0f + expf(-x)); }
__device__ __forceinline__ short bfr(float x) {
  __hip_bfloat16 h = __float2bfloat16(x);
  return *(short*)&h;
}

// ---- prep: W1b = bf16([W_ih | W_hh]) rows n=0..2047; b1 = b_ih + b_hh -------------------
__global__ __launch_bounds__(256) void prep_w1b(const float* __restrict__ Wih,
                                                const float* __restrict__ Whh,
                                                const float* __restrict__ bih,
                                                const float* __restrict__ bhh,
                                                short* __restrict__ W1b,
                                                float* __restrict__ b1) {
  int idx = blockIdx.x * 256 + threadIdx.x;
  if (idx < NG * KA) {
    int n = idx / KA, k = idx - n * KA;
    float w = (k < 640) ? Wih[(size_t)n * 640 + k] : Whh[(size_t)n * 512 + (k - 640)];
    W1b[idx] = bfr(w);
    if (k == 0) b1[n] = bih[n] + bhh[n];
  }
}
__global__ __launch_bounds__(256) void prep_bf(const float* __restrict__ src,
                                               short* __restrict__ dst, int n) {
  int idx = blockIdx.x * 256 + threadIdx.x;
  if (idx < n) dst[idx] = bfr(src[idx]);
}

// ---- init: A2bf = [*, 0, bf16(h0)], Hst = h0, C = c0 ------------------------------------
__global__ __launch_bounds__(256) void init2(const float* __restrict__ h0,
                                             const float* __restrict__ c0,
                                             short* __restrict__ A2bf,
                                             float* __restrict__ Hst,
                                             float* __restrict__ C) {
  int idx = blockIdx.x * 256 + threadIdx.x;
  int b = idx >> 9, k = idx & 511;
  A2bf[(size_t)b * KA + CTXO + k] = 0;
  A2bf[(size_t)b * KA + HOFF + k] = bfr(h0[idx]);
  Hst[idx] = h0[idx];
  C[idx] = c0[idx];
}

// ---- A2bf[b][0:128] = bf16(emb[seq[b][t]]) ----------------------------------------------
__global__ __launch_bounds__(256) void embed2(const int* __restrict__ seq,
                                              const float* __restrict__ emb,
                                              short* __restrict__ A2bf, int t) {
  int idx = blockIdx.x * 256 + threadIdx.x;
  int b = idx >> 7, k = idx & 127;
  int tok = seq[b * SL + t];
  A2bf[(size_t)b * KA + k] = bfr(emb[(size_t)tok * EMBD + k]);
}

// ---- MFMA NT GEMM: C[M][N] = A[M][K] * B[N][K]^T (+bias), bf16 in, f32/bf16 out ---------
// BM=64, BK=32; 4 waves in 2x2; wave computes 32 x (BN/2).
template <int BN, bool AF32, bool BF16_OUT, bool HAS_BIAS>
__global__ __launch_bounds__(256) void gemm_mfma(const void* __restrict__ Ap, int lda,
                                                 const short* __restrict__ B, int ldb,
                                                 const float* __restrict__ bias,
                                                 void* __restrict__ Cp, int ldc, int K) {
  constexpr int BM = 64, WN = BN / 2, NF = WN / 16;
  __shared__ __align__(16) short As[BM][48];
  __shared__ __align__(16) short Bs[BN][48];
  const int tid = threadIdx.x;
  const int lane = tid & 63, wave = tid >> 6;
  const int wr = wave >> 1, wc = wave & 1;
  const int m0 = blockIdx.y * BM, n0 = blockIdx.x * BN;
  f32x4 acc[2][NF];
  #pragma unroll
  for (int i = 0; i < 2; ++i)
    #pragma unroll
    for (int j = 0; j < NF; ++j) acc[i][j] = (f32x4){0.f, 0.f, 0.f, 0.f};

  const int sar = tid >> 2, sac = (tid & 3) * 8;
  const int lr = lane & 15, lk = (lane >> 4) * 8;

  for (int kt = 0; kt < K; kt += 32) {
    if (AF32) {
      const float* A = (const float*)Ap;
      const float* src = &A[(size_t)(m0 + sar) * lda + kt + sac];
      short8v v;
      #pragma unroll
      for (int q = 0; q < 8; ++q) v[q] = bfr(src[q]);
      *(short8v*)&As[sar][sac] = v;
    } else {
      const short* A = (const short*)Ap;
      *(uint4*)&As[sar][sac] = *(const uint4*)&A[(size_t)(m0 + sar) * lda + kt + sac];
    }
    #pragma unroll
    for (int c = 0; c < BN / 64; ++c) {
      int chunk = tid + c * 256;
      int br = chunk >> 2, bc = (chunk & 3) * 8;
      *(uint4*)&Bs[br][bc] = *(const uint4*)&B[(size_t)(n0 + br) * ldb + kt + bc];
    }
    __syncthreads();
    short8v a[2], b[NF];
    #pragma unroll
    for (int i = 0; i < 2; ++i)
      a[i] = *(const short8v*)&As[wr * 32 + i * 16 + lr][lk];
    #pragma unroll
    for (int j = 0; j < NF; ++j)
      b[j] = *(const short8v*)&Bs[wc * WN + j * 16 + lr][lk];
    #pragma unroll
    for (int i = 0; i < 2; ++i)
      #pragma unroll
      for (int j = 0; j < NF; ++j)
        acc[i][j] = __builtin_amdgcn_mfma_f32_16x16x32_bf16(a[i], b[j], acc[i][j], 0, 0, 0);
    __syncthreads();
  }

  #pragma unroll
  for (int i = 0; i < 2; ++i)
    #pragma unroll
    for (int j = 0; j < NF; ++j) {
      int gc = n0 + wc * WN + j * 16 + (lane & 15);
      float bv = HAS_BIAS ? bias[gc] : 0.f;
      #pragma unroll
      for (int r = 0; r < 4; ++r) {
        int gr = m0 + wr * 32 + i * 16 + (lane >> 4) * 4 + r;
        float v = acc[i][j][r] + bv;
        if (BF16_OUT) ((short*)Cp)[(size_t)gr * ldc + gc] = bfr(v);
        else          ((float*)Cp)[(size_t)gr * ldc + gc] = v;
      }
    }
}

// ---- LSTM cell ---------------------------------------------------------------------------
__global__ __launch_bounds__(256) void cell2(const float* __restrict__ gates,
                                             float* __restrict__ C,
                                             float* __restrict__ Hst,
                                             short* __restrict__ A2bf,
                                             short* __restrict__ hcatbf,
                                             float* __restrict__ outp,
                                             const int* __restrict__ lens, int t) {
  int idx = blockIdx.x * 256 + threadIdx.x;
  int b = idx >> 9, j = idx & 511;
  size_t gb = (size_t)b * NG;
  float gi = gates[gb + j], gf = gates[gb + 512 + j];
  float gg = gates[gb + 1024 + j], go = gates[gb + 1536 + j];
  float co = C[idx];
  float cn = sigmf(gf) * co + sigmf(gi) * tanhf(gg);
  float hn = sigmf(go) * tanhf(cn);
  hcatbf[(size_t)b * 1024 + j] = bfr(hn);
  hcatbf[(size_t)b * 1024 + 512 + j] = bfr(cn);
  bool am = t < lens[b];
  if (am) {
    A2bf[(size_t)b * KA + HOFF + j] = bfr(hn);
    C[idx] = cn;
    Hst[idx] = hn;
  }
  outp[((size_t)b * SL + t) * HIDN + j] = am ? hn : 0.0f;
}

// ---- attention ---------------------------------------------------------------------------
__global__ __launch_bounds__(256) void attn_row(const float* __restrict__ dec,
                                                const __hip_bfloat16* __restrict__ ef,
                                                const float* __restrict__ attn,
                                                const float* __restrict__ mask,
                                                const int* __restrict__ lens,
                                                short* __restrict__ A2bf,
                                                const float* __restrict__ v, int t) {
  __shared__ float sdec[HIDN];
  __shared__ float sv[HIDN];
  __shared__ float sa[SL];
  const int b = blockIdx.x;
  for (int k = threadIdx.x; k < HIDN; k += 256) {
    sdec[k] = dec[(size_t)b * HIDN + k];
    sv[k] = v[k];
  }
  __syncthreads();
  if (threadIdx.x < 64) {
    const int tt = threadIdx.x;
    float s = -1e30f;
    if (tt < SL) {
      s = 0.f;
      const __hip_bfloat16* er = ef + ((size_t)b * SL + tt) * HIDN;
      for (int k = 0; k < HIDN; ++k)
        s += sv[k] * tanhf(__bfloat162float(er[k]) + sdec[k]);
    }
    float mx = s;
    #pragma unroll
    for (int off = 32; off >= 1; off >>= 1) mx = fmaxf(mx, __shfl_xor(mx, off, 64));
    float e = (tt < SL) ? expf(s - mx) * mask[b * SL + tt] : 0.f;
    float sum = e;
    #pragma unroll
    for (int off = 32; off >= 1; off >>= 1) sum += __shfl_xor(sum, off, 64);
    if (tt < SL) sa[tt] = e / sum;
  }
  __syncthreads();
  if (t < lens[b]) {
    for (int j = threadIdx.x; j < HIDN; j += 256) {
      float cx = 0.f;
      for (int tt = 0; tt < SL; ++tt)
        cx += sa[tt] * attn[((size_t)b * SL + tt) * HIDN + j];
      A2bf[(size_t)b * KA + CTXO + j] = bfr(cx);
    }
  }
}

// ---- final h, c --------------------------------------------------------------------------
__global__ __launch_bounds__(256) void fin2(const float* __restrict__ Hst,
                                            const float* __restrict__ C,
                                            float* __restrict__ outp) {
  int idx = blockIdx.x * 256 + threadIdx.x;
  outp[HPOS + idx] = Hst[idx];
  outp[CPOS + idx] = C[idx];
}

extern "C" void kernel_launch(void* const* d_in, const int* in_sizes, int n_in,
                              void* d_out, int out_size, void* d_ws, size_t ws_size,
                              hipStream_t stream) {
  (void)in_sizes; (void)n_in; (void)out_size; (void)ws_size;
  const int*   seq  = (const int*)d_in[0];
  const int*   lens = (const int*)d_in[1];
  const float* h0   = (const float*)d_in[2];
  const float* c0   = (const float*)d_in[3];
  const float* attn = (const float*)d_in[4];
  const float* mask = (const float*)d_in[5];
  const float* emb  = (const float*)d_in[6];
  const float* W_ih = (const float*)d_in[7];
  const float* W_hh = (const float*)d_in[8];
  const float* b_ih = (const float*)d_in[9];
  const float* b_hh = (const float*)d_in[10];
  const float* Wh   = (const float*)d_in[11];
  const float* Wdp  = (const float*)d_in[12];
  const float* bdp  = (const float*)d_in[13];
  const float* vv   = (const float*)d_in[14];
  float* outp = (float*)d_out;

  float* ws = (float*)d_ws;
  short* W1b    = (short*)(ws);                    // 2359296 sh = 1179648 f
  short* Wdpb   = (short*)(ws + 1179648);          // 524288 sh  = 262144 f
  short* Whb    = (short*)(ws + 1441792);          // 262144 sh  = 131072 f
  __hip_bfloat16* ef = (__hip_bfloat16*)(ws + 1572864);  // 25165824 sh = 12582912 f
  short* A2bf   = (short*)(ws + 14155776);         // 1179648 sh = 589824 f
  short* hcatbf = (short*)(ws + 14745600);         // 1048576 sh = 524288 f
  float* b1     = ws + 15269888;                   // 2048
  float* Hst    = ws + 15271936;                   // 524288
  float* C      = ws + 15796224;                   // 524288
  float* gates  = ws + 16320512;                   // 2097152
  float* dec    = ws + 18417664;                   // 524288  (end 18941952 f = 75.8 MB)

  prep_w1b<<<(NG * KA + 255) / 256, 256, 0, stream>>>(W_ih, W_hh, b_ih, b_hh, W1b, b1);
  prep_bf<<<(512 * 1024 + 255) / 256, 256, 0, stream>>>(Wdp, Wdpb, 512 * 1024);
  prep_bf<<<(512 * 512 + 255) / 256, 256, 0, stream>>>(Wh, Whb, 512 * 512);
  // ef = attn @ Wh^T  (49152 x 512, K=512), f32 A converted in staging, bf16 out
  gemm_mfma<128, true, true, false><<<dim3(512 / 128, (NB * SL) / 64), 256, 0, stream>>>(
      attn, HIDN, Whb, HIDN, nullptr, ef, HIDN, HIDN);
  init2<<<(NB * HIDN) / 256, 256, 0, stream>>>(h0, c0, A2bf, Hst, C);

  for (int t = 0; t < SL; ++t) {
    embed2<<<(NB * EMBD) / 256, 256, 0, stream>>>(seq, emb, A2bf, t);
    // gates = A2bf @ W1b^T + b1  (1024 x 2048, K=1152)
    gemm_mfma<128, false, false, true><<<dim3(NG / 128, NB / 64), 256, 0, stream>>>(
        A2bf, KA, W1b, KA, b1, gates, NG, KA);
    cell2<<<(NB * HIDN) / 256, 256, 0, stream>>>(gates, C, Hst, A2bf, hcatbf, outp, lens, t);
    // dec = hcatbf @ Wdpb^T + bdp  (1024 x 512, K=1024)
    gemm_mfma<64, false, false, true><<<dim3(HIDN / 64, NB / 64), 256, 0, stream>>>(
        hcatbf, 1024, Wdpb, 1024, bdp, dec, HIDN, 1024);
    attn_row<<<NB, 256, 0, stream>>>(dec, ef, attn, mask, lens, A2bf, vv, t);
  }
  fin2<<<(NB * HIDN) / 256, 256, 0, stream>>>(Hst, C, outp);
}

// Round 16
// 5921.361 us; speedup vs baseline: 2.3890x; 1.0008x over previous
//
#include <hip/hip_runtime.h>
#include <hip/hip_bf16.h>

#define HIDN 512
#define EMBD 128
#define NB   1024
#define SL   48
#define NG   2048
#define KA2  1024   // A2 row = [ctx(512) | h(512)]

// d_out FLOAT32: [ output (B,L,H) | h_final (1,B,H) | c_final (1,B,H) ]
#define HPOS ((size_t)25165824)
#define CPOS ((size_t)25690112)

typedef __attribute__((ext_vector_type(8))) short short8v;
typedef __attribute__((ext_vector_type(4))) float f32x4;

__device__ __forceinline__ float sigmf(float x) { return 1.0f / (1.0f + expf(-x)); }
__device__ __forceinline__ short bfr(float x) {
  __hip_bfloat16 h = __float2bfloat16(x);
  return *(short*)&h;
}

// ---- W1p[n'][k]: gate-permuted n'=4j+g (r=g*512+j); k<512 ctx-weights, k>=512 h-weights --
__global__ __launch_bounds__(256) void prep_w1p(const float* __restrict__ Wih,
                                                const float* __restrict__ Whh,
                                                short* __restrict__ W1p) {
  int idx = blockIdx.x * 256 + threadIdx.x;
  if (idx < NG * KA2) {
    int n = idx >> 10, k = idx & 1023;
    int j = n >> 2, g = n & 3, r = g * 512 + j;
    float w = (k < 512) ? Wih[(size_t)r * 640 + 128 + k] : Whh[(size_t)r * 512 + (k - 512)];
    W1p[idx] = bfr(w);
  }
}

// ---- embW[v][n'] = emb[v]·W_ih[r,0:128] + b_ih[r] + b_hh[r]  (f32, exact) ---------------
__global__ __launch_bounds__(256) void prep_embw(const float* __restrict__ emb,
                                                 const float* __restrict__ Wih,
                                                 const float* __restrict__ bih,
                                                 const float* __restrict__ bhh,
                                                 float* __restrict__ embW) {
  __shared__ float se[EMBD];
  int v = blockIdx.y;
  if (threadIdx.x < EMBD) se[threadIdx.x] = emb[(size_t)v * EMBD + threadIdx.x];
  __syncthreads();
  int n = blockIdx.x * 256 + threadIdx.x;
  int j = n >> 2, g = n & 3, r = g * 512 + j;
  float acc = bih[r] + bhh[r];
  const float* w = Wih + (size_t)r * 640;
  for (int k = 0; k < EMBD; ++k) acc += se[k] * w[k];
  embW[(size_t)v * NG + n] = acc;
}

__global__ __launch_bounds__(256) void prep_bf(const float* __restrict__ src,
                                               short* __restrict__ dst, int n) {
  int idx = blockIdx.x * 256 + threadIdx.x;
  if (idx < n) dst[idx] = bfr(src[idx]);
}

// ---- init: A2[0] = [ctx=0 | bf16(h0)], Hst = h0, C = c0 ---------------------------------
__global__ __launch_bounds__(256) void init2(const float* __restrict__ h0,
                                             const float* __restrict__ c0,
                                             short* __restrict__ A2,
                                             float* __restrict__ Hst,
                                             float* __restrict__ C) {
  int idx = blockIdx.x * 256 + threadIdx.x;
  int b = idx >> 9, k = idx & 511;
  A2[(size_t)b * KA2 + k] = 0;
  A2[(size_t)b * KA2 + 512 + k] = bfr(h0[idx]);
  Hst[idx] = h0[idx];
  C[idx] = c0[idx];
}

// ---- generic MFMA NT GEMM (ef, dec): C[M][N] = A[M][K]*B[N][K]^T (+bias) ----------------
template <int BN, bool AF32, bool BF16_OUT, bool HAS_BIAS>
__global__ __launch_bounds__(256) void gemm_mfma(const void* __restrict__ Ap, int lda,
                                                 const short* __restrict__ B, int ldb,
                                                 const float* __restrict__ bias,
                                                 void* __restrict__ Cp, int ldc, int K) {
  constexpr int BM = 64, WN = BN / 2, NF = WN / 16;
  __shared__ __align__(16) short As[BM][48];
  __shared__ __align__(16) short Bs[BN][48];
  const int tid = threadIdx.x;
  const int lane = tid & 63, wave = tid >> 6;
  const int wr = wave >> 1, wc = wave & 1;
  const int m0 = blockIdx.y * BM, n0 = blockIdx.x * BN;
  f32x4 acc[2][NF];
  #pragma unroll
  for (int i = 0; i < 2; ++i)
    #pragma unroll
    for (int j = 0; j < NF; ++j) acc[i][j] = (f32x4){0.f, 0.f, 0.f, 0.f};

  const int sar = tid >> 2, sac = (tid & 3) * 8;
  const int lr = lane & 15, lk = (lane >> 4) * 8;

  for (int kt = 0; kt < K; kt += 32) {
    if (AF32) {
      const float* A = (const float*)Ap;
      const float* src = &A[(size_t)(m0 + sar) * lda + kt + sac];
      short8v v;
      #pragma unroll
      for (int q = 0; q < 8; ++q) v[q] = bfr(src[q]);
      *(short8v*)&As[sar][sac] = v;
    } else {
      const short* A = (const short*)Ap;
      *(uint4*)&As[sar][sac] = *(const uint4*)&A[(size_t)(m0 + sar) * lda + kt + sac];
    }
    #pragma unroll
    for (int c = 0; c < BN / 64; ++c) {
      int chunk = tid + c * 256;
      int br = chunk >> 2, bc = (chunk & 3) * 8;
      *(uint4*)&Bs[br][bc] = *(const uint4*)&B[(size_t)(n0 + br) * ldb + kt + bc];
    }
    __syncthreads();
    short8v a[2], b[NF];
    #pragma unroll
    for (int i = 0; i < 2; ++i)
      a[i] = *(const short8v*)&As[wr * 32 + i * 16 + lr][lk];
    #pragma unroll
    for (int j = 0; j < NF; ++j)
      b[j] = *(const short8v*)&Bs[wc * WN + j * 16 + lr][lk];
    #pragma unroll
    for (int i = 0; i < 2; ++i)
      #pragma unroll
      for (int j = 0; j < NF; ++j)
        acc[i][j] = __builtin_amdgcn_mfma_f32_16x16x32_bf16(a[i], b[j], acc[i][j], 0, 0, 0);
    __syncthreads();
  }

  #pragma unroll
  for (int i = 0; i < 2; ++i)
    #pragma unroll
    for (int j = 0; j < NF; ++j) {
      int gc = n0 + wc * WN + j * 16 + (lane & 15);
      float bv = HAS_BIAS ? bias[gc] : 0.f;
      #pragma unroll
      for (int r = 0; r < 4; ++r) {
        int gr = m0 + wr * 32 + i * 16 + (lane >> 4) * 4 + r;
        float v = acc[i][j][r] + bv;
        if (BF16_OUT) ((short*)Cp)[(size_t)gr * ldc + gc] = bfr(v);
        else          ((float*)Cp)[(size_t)gr * ldc + gc] = v;
      }
    }
}

// ---- FUSED gates GEMM + LSTM cell. BM=64, BN=128 (32 units), gate-permuted weights ------
// XCD swizzle: bid%8 -> 2-column stripe; per-XCD L2 holds its W-stripe + full A.
__global__ __launch_bounds__(256) void gates_cell_f(const short* __restrict__ A2cur,
                                                    short* __restrict__ A2nxt,
                                                    const short* __restrict__ W1p,
                                                    const float* __restrict__ embW,
                                                    const int* __restrict__ seq,
                                                    const int* __restrict__ lens,
                                                    float* __restrict__ C,
                                                    float* __restrict__ Hst,
                                                    short* __restrict__ hcatbf,
                                                    float* __restrict__ outp, int t) {
  __shared__ __align__(16) short As[64][48];
  __shared__ __align__(16) short Bs[128][48];
  __shared__ __align__(16) float sAcc[64][132];
  const int tid = threadIdx.x;
  const int lane = tid & 63, wave = tid >> 6;
  const int wr = wave >> 1, wc = wave & 1;
  const int bid = blockIdx.x;
  const int col = ((bid & 7) << 1) | ((bid >> 3) & 1);   // 0..15
  const int row = bid >> 4;                              // 0..15
  const int m0 = row * 64, n0 = col * 128;
  f32x4 acc[2][4];
  #pragma unroll
  for (int i = 0; i < 2; ++i)
    #pragma unroll
    for (int j = 0; j < 4; ++j) acc[i][j] = (f32x4){0.f, 0.f, 0.f, 0.f};

  const int sar = tid >> 2, sac = (tid & 3) * 8;
  const int lr = lane & 15, lk = (lane >> 4) * 8;

  for (int kt = 0; kt < KA2; kt += 32) {
    *(uint4*)&As[sar][sac] = *(const uint4*)&A2cur[(size_t)(m0 + sar) * KA2 + kt + sac];
    #pragma unroll
    for (int c = 0; c < 2; ++c) {
      int chunk = tid + c * 256;
      int br = chunk >> 2, bc = (chunk & 3) * 8;
      *(uint4*)&Bs[br][bc] = *(const uint4*)&W1p[(size_t)(n0 + br) * KA2 + kt + bc];
    }
    __syncthreads();
    short8v a[2], b[4];
    #pragma unroll
    for (int i = 0; i < 2; ++i)
      a[i] = *(const short8v*)&As[wr * 32 + i * 16 + lr][lk];
    #pragma unroll
    for (int j = 0; j < 4; ++j)
      b[j] = *(const short8v*)&Bs[wc * 64 + j * 16 + lr][lk];
    #pragma unroll
    for (int i = 0; i < 2; ++i)
      #pragma unroll
      for (int j = 0; j < 4; ++j)
        acc[i][j] = __builtin_amdgcn_mfma_f32_16x16x32_bf16(a[i], b[j], acc[i][j], 0, 0, 0);
    __syncthreads();
  }

  // stage accumulators to LDS
  #pragma unroll
  for (int i = 0; i < 2; ++i)
    #pragma unroll
    for (int j = 0; j < 4; ++j)
      #pragma unroll
      for (int r = 0; r < 4; ++r)
        sAcc[wr * 32 + i * 16 + (lane >> 4) * 4 + r][wc * 64 + j * 16 + (lane & 15)] =
            acc[i][j][r];
  __syncthreads();

  // fused LSTM cell: thread -> row bl = tid>>2, units (tid&3)*8 .. +8
  const int bl = tid >> 2;
  const int gb = m0 + bl;
  const int ju0 = (tid & 3) * 8;
  const int tok = seq[gb * SL + t];
  const bool am = t < lens[gb];
  const float* ewr = embW + (size_t)tok * NG + n0;
  #pragma unroll
  for (int u = 0; u < 8; ++u) {
    int jl = ju0 + u;
    int jg = (n0 >> 2) + jl;
    f32x4 ew = *(const f32x4*)&ewr[jl * 4];
    f32x4 g4 = *(const f32x4*)&sAcc[bl][jl * 4];
    float gi = g4.x + ew.x, gf = g4.y + ew.y, gg = g4.z + ew.z, go = g4.w + ew.w;
    size_t cix = (size_t)gb * 512 + jg;
    float co = C[cix];
    float cn = sigmf(gf) * co + sigmf(gi) * tanhf(gg);
    float hn = sigmf(go) * tanhf(cn);
    hcatbf[(size_t)gb * 1024 + jg] = bfr(hn);
    hcatbf[(size_t)gb * 1024 + 512 + jg] = bfr(cn);
    short hv;
    if (am) { C[cix] = cn; Hst[cix] = hn; hv = bfr(hn); }
    else hv = A2cur[(size_t)gb * KA2 + 512 + jg];
    A2nxt[(size_t)gb * KA2 + 512 + jg] = hv;
    outp[((size_t)gb * SL + t) * 512 + jg] = am ? hn : 0.0f;
  }
}

// ---- attention: scores + softmax + ctx -> A2nxt ctx part (both mask branches) -----------
__global__ __launch_bounds__(256) void attn_row(const float* __restrict__ dec,
                                                const __hip_bfloat16* __restrict__ ef,
                                                const float* __restrict__ attn,
                                                const float* __restrict__ mask,
                                                const int* __restrict__ lens,
                                                const short* __restrict__ A2cur,
                                                short* __restrict__ A2nxt,
                                                const float* __restrict__ v, int t) {
  __shared__ float sdec[HIDN];
  __shared__ float sv[HIDN];
  __shared__ float sa[SL];
  const int b = blockIdx.x;
  for (int k = threadIdx.x; k < HIDN; k += 256) {
    sdec[k] = dec[(size_t)b * HIDN + k];
    sv[k] = v[k];
  }
  __syncthreads();
  if (threadIdx.x < 64) {
    const int tt = threadIdx.x;
    float s = -1e30f;
    if (tt < SL) {
      s = 0.f;
      const __hip_bfloat16* er = ef + ((size_t)b * SL + tt) * HIDN;
      for (int k = 0; k < HIDN; ++k)
        s += sv[k] * tanhf(__bfloat162float(er[k]) + sdec[k]);
    }
    float mx = s;
    #pragma unroll
    for (int off = 32; off >= 1; off >>= 1) mx = fmaxf(mx, __shfl_xor(mx, off, 64));
    float e = (tt < SL) ? expf(s - mx) * mask[b * SL + tt] : 0.f;
    float sum = e;
    #pragma unroll
    for (int off = 32; off >= 1; off >>= 1) sum += __shfl_xor(sum, off, 64);
    if (tt < SL) sa[tt] = e / sum;
  }
  __syncthreads();
  const bool am = t < lens[b];
  for (int j = threadIdx.x; j < HIDN; j += 256) {
    short cv;
    if (am) {
      float cx = 0.f;
      for (int tt = 0; tt < SL; ++tt)
        cx += sa[tt] * attn[((size_t)b * SL + tt) * HIDN + j];
      cv = bfr(cx);
    } else {
      cv = A2cur[(size_t)b * KA2 + j];
    }
    A2nxt[(size_t)b * KA2 + j] = cv;
  }
}

// ---- final h, c --------------------------------------------------------------------------
__global__ __launch_bounds__(256) void fin2(const float* __restrict__ Hst,
                                            const float* __restrict__ C,
                                            float* __restrict__ outp) {
  int idx = blockIdx.x * 256 + threadIdx.x;
  outp[HPOS + idx] = Hst[idx];
  outp[CPOS + idx] = C[idx];
}

extern "C" void kernel_launch(void* const* d_in, const int* in_sizes, int n_in,
                              void* d_out, int out_size, void* d_ws, size_t ws_size,
                              hipStream_t stream) {
  (void)in_sizes; (void)n_in; (void)out_size; (void)ws_size;
  const int*   seq  = (const int*)d_in[0];
  const int*   lens = (const int*)d_in[1];
  const float* h0   = (const float*)d_in[2];
  const float* c0   = (const float*)d_in[3];
  const float* attn = (const float*)d_in[4];
  const float* mask = (const float*)d_in[5];
  const float* emb  = (const float*)d_in[6];
  const float* W_ih = (const float*)d_in[7];
  const float* W_hh = (const float*)d_in[8];
  const float* b_ih = (const float*)d_in[9];
  const float* b_hh = (const float*)d_in[10];
  const float* Wh   = (const float*)d_in[11];
  const float* Wdp  = (const float*)d_in[12];
  const float* bdp  = (const float*)d_in[13];
  const float* vv   = (const float*)d_in[14];
  float* outp = (float*)d_out;

  float* ws = (float*)d_ws;
  short* W1p    = (short*)(ws);                          // 2048*1024 sh = 1048576 f
  short* Wdpb   = (short*)(ws + 1048576);                // 512*1024 sh = 262144 f
  short* Whb    = (short*)(ws + 1310720);                // 512*512 sh = 131072 f
  float* embW   = ws + 1441792;                          // 620*2048 f = 1269760 f
  __hip_bfloat16* ef = (__hip_bfloat16*)(ws + 2711552);  // 49152*512 sh = 12582912 f
  short* A2b[2] = { (short*)(ws + 15294464), (short*)(ws + 15818752) };  // 2x 524288 f
  short* hcatbf = (short*)(ws + 16343040);               // 524288 f
  float* Hst    = ws + 16867328;                         // 524288
  float* C      = ws + 17391616;                         // 524288
  float* dec    = ws + 17915904;                         // 524288  (end 18440192 f = 73.8 MB)

  prep_w1p<<<(NG * KA2 + 255) / 256, 256, 0, stream>>>(W_ih, W_hh, W1p);
  prep_embw<<<dim3(NG / 256, 620), 256, 0, stream>>>(emb, W_ih, b_ih, b_hh, embW);
  prep_bf<<<(512 * 1024 + 255) / 256, 256, 0, stream>>>(Wdp, Wdpb, 512 * 1024);
  prep_bf<<<(512 * 512 + 255) / 256, 256, 0, stream>>>(Wh, Whb, 512 * 512);
  // ef = attn @ Wh^T  (49152 x 512, K=512), bf16 out
  gemm_mfma<128, true, true, false><<<dim3(512 / 128, (NB * SL) / 64), 256, 0, stream>>>(
      attn, HIDN, Whb, HIDN, nullptr, ef, HIDN, HIDN);
  init2<<<(NB * HIDN) / 256, 256, 0, stream>>>(h0, c0, A2b[0], Hst, C);

  for (int t = 0; t < SL; ++t) {
    int cur = t & 1, nxt = cur ^ 1;
    gates_cell_f<<<256, 256, 0, stream>>>(A2b[cur], A2b[nxt], W1p, embW, seq, lens,
                                          C, Hst, hcatbf, outp, t);
    // dec = hcatbf @ Wdpb^T + bdp  (1024 x 512, K=1024)
    gemm_mfma<64, false, false, true><<<dim3(HIDN / 64, NB / 64), 256, 0, stream>>>(
        hcatbf, 1024, Wdpb, 1024, bdp, dec, HIDN, 1024);
    attn_row<<<NB, 256, 0, stream>>>(dec, ef, attn, mask, lens, A2b[cur], A2b[nxt], vv, t);
  }
  fin2<<<(NB * HIDN) / 256, 256, 0, stream>>>(Hst, C, outp);
}

// Round 17
// 4126.470 us; speedup vs baseline: 3.4281x; 1.4350x over previous
//
#include <hip/hip_runtime.h>
#include <hip/hip_bf16.h>

#define HIDN 512
#define EMBD 128
#define NB   1024
#define SL   48
#define NG   2048
#define KA2  1024   // A2 row = [ctx(512) | h(512)]

// d_out FLOAT32: [ output (B,L,H) | h_final (1,B,H) | c_final (1,B,H) ]
#define HPOS ((size_t)25165824)
#define CPOS ((size_t)25690112)

typedef __attribute__((ext_vector_type(8))) short short8v;
typedef __attribute__((ext_vector_type(4))) float f32x4;

__device__ __forceinline__ float sigmf(float x) { return 1.0f / (1.0f + expf(-x)); }
__device__ __forceinline__ short bfr(float x) {
  __hip_bfloat16 h = __float2bfloat16(x);
  return *(short*)&h;
}
__device__ __forceinline__ float bf2f(unsigned short u) {
  union { unsigned int i; float f; } c;
  c.i = ((unsigned int)u) << 16;
  return c.f;
}

// ---- W1p[n'][k]: gate-permuted n'=4j+g (r=g*512+j); k<512 ctx, k>=512 h -----------------
__global__ __launch_bounds__(256) void prep_w1p(const float* __restrict__ Wih,
                                                const float* __restrict__ Whh,
                                                short* __restrict__ W1p) {
  int idx = blockIdx.x * 256 + threadIdx.x;
  if (idx < NG * KA2) {
    int n = idx >> 10, k = idx & 1023;
    int j = n >> 2, g = n & 3, r = g * 512 + j;
    float w = (k < 512) ? Wih[(size_t)r * 640 + 128 + k] : Whh[(size_t)r * 512 + (k - 512)];
    W1p[idx] = bfr(w);
  }
}

// ---- Wxpb[n'][0:128] = bf16(W_ih[r][0:128]); bperm[n'] = b_ih[r]+b_hh[r] ----------------
__global__ __launch_bounds__(256) void prep_wxp(const float* __restrict__ Wih,
                                                const float* __restrict__ bih,
                                                const float* __restrict__ bhh,
                                                short* __restrict__ Wxpb,
                                                float* __restrict__ bperm) {
  int idx = blockIdx.x * 256 + threadIdx.x;
  if (idx < NG * EMBD) {
    int n = idx >> 7, k = idx & 127;
    int j = n >> 2, g = n & 3, r = g * 512 + j;
    Wxpb[idx] = bfr(Wih[(size_t)r * 640 + k]);
    if (k == 0) bperm[n] = bih[r] + bhh[r];
  }
}

// ---- embbf[640][128] = bf16(emb) padded with zeros --------------------------------------
__global__ __launch_bounds__(256) void prep_embb(const float* __restrict__ emb,
                                                 short* __restrict__ embbf) {
  int idx = blockIdx.x * 256 + threadIdx.x;
  if (idx < 640 * EMBD) {
    int v = idx >> 7;
    embbf[idx] = (v < 620) ? bfr(emb[idx]) : (short)0;
  }
}

__global__ __launch_bounds__(256) void prep_bf(const float* __restrict__ src,
                                               short* __restrict__ dst, int n) {
  int idx = blockIdx.x * 256 + threadIdx.x;
  if (idx < n) dst[idx] = bfr(src[idx]);
}

// ---- init: A2[0] = [ctx=0 | bf16(h0)], Hst = h0, C = c0 ---------------------------------
__global__ __launch_bounds__(256) void init2(const float* __restrict__ h0,
                                             const float* __restrict__ c0,
                                             short* __restrict__ A2,
                                             float* __restrict__ Hst,
                                             float* __restrict__ C) {
  int idx = blockIdx.x * 256 + threadIdx.x;
  int b = idx >> 9, k = idx & 511;
  A2[(size_t)b * KA2 + k] = 0;
  A2[(size_t)b * KA2 + 512 + k] = bfr(h0[idx]);
  Hst[idx] = h0[idx];
  C[idx] = c0[idx];
}

// ---- generic pipelined MFMA NT GEMM: C[M][N] = A[M][K]*B[N][K]^T (+bias) ----------------
template <int BN, bool AF32, bool BF16_OUT, bool HAS_BIAS>
__global__ __launch_bounds__(256) void gemm_mfma(const void* __restrict__ Ap, int lda,
                                                 const short* __restrict__ B, int ldb,
                                                 const float* __restrict__ bias,
                                                 void* __restrict__ Cp, int ldc, int K) {
  constexpr int BM = 64, WN = BN / 2, NF = WN / 16, NBC = BN / 64;
  __shared__ __align__(16) short As[BM][40];
  __shared__ __align__(16) short Bs[BN][40];
  const int tid = threadIdx.x;
  const int lane = tid & 63, wave = tid >> 6;
  const int wr = wave >> 1, wc = wave & 1;
  const int m0 = blockIdx.y * BM, n0 = blockIdx.x * BN;
  f32x4 acc[2][NF];
  #pragma unroll
  for (int i = 0; i < 2; ++i)
    #pragma unroll
    for (int j = 0; j < NF; ++j) acc[i][j] = (f32x4){0.f, 0.f, 0.f, 0.f};
  const int sar = tid >> 2, sac = (tid & 3) * 8;
  const int lr = lane & 15, lk = (lane >> 4) * 8;
  const int nk = K / 32;
  uint4 pa0, pa1, pb[NBC];

#define LOADG(KT)                                                                   \
  {                                                                                 \
    if (AF32) {                                                                     \
      const float* A = (const float*)Ap;                                            \
      const float* srcp = &A[(size_t)(m0 + sar) * lda + (KT) * 32 + sac];           \
      pa0 = *(const uint4*)&srcp[0];                                                \
      pa1 = *(const uint4*)&srcp[4];                                                \
    } else {                                                                        \
      const short* A = (const short*)Ap;                                            \
      pa0 = *(const uint4*)&A[(size_t)(m0 + sar) * lda + (KT) * 32 + sac];          \
    }                                                                               \
    _Pragma("unroll")                                                               \
    for (int c = 0; c < NBC; ++c) {                                                 \
      int chunk = tid + c * 256;                                                    \
      int br = chunk >> 2, bc = (chunk & 3) * 8;                                    \
      pb[c] = *(const uint4*)&B[(size_t)(n0 + br) * ldb + (KT) * 32 + bc];          \
    }                                                                               \
  }
#define STOREL()                                                                    \
  {                                                                                 \
    if (AF32) {                                                                     \
      const float* f0 = (const float*)&pa0;                                         \
      const float* f1 = (const float*)&pa1;                                         \
      short8v vv8;                                                                  \
      vv8[0] = bfr(f0[0]); vv8[1] = bfr(f0[1]); vv8[2] = bfr(f0[2]);                \
      vv8[3] = bfr(f0[3]); vv8[4] = bfr(f1[0]); vv8[5] = bfr(f1[1]);                \
      vv8[6] = bfr(f1[2]); vv8[7] = bfr(f1[3]);                                     \
      *(short8v*)&As[sar][sac] = vv8;                                               \
    } else {                                                                        \
      *(uint4*)&As[sar][sac] = pa0;                                                 \
    }                                                                               \
    _Pragma("unroll")                                                               \
    for (int c = 0; c < NBC; ++c) {                                                 \
      int chunk = tid + c * 256;                                                    \
      int br = chunk >> 2, bc = (chunk & 3) * 8;                                    \
      *(uint4*)&Bs[br][bc] = pb[c];                                                 \
    }                                                                               \
  }

  LOADG(0);
  STOREL();
  __syncthreads();
  for (int kt = 0; kt < nk; ++kt) {
    if (kt + 1 < nk) LOADG(kt + 1);
    short8v a[2], b[NF];
    #pragma unroll
    for (int i = 0; i < 2; ++i)
      a[i] = *(const short8v*)&As[wr * 32 + i * 16 + lr][lk];
    #pragma unroll
    for (int j = 0; j < NF; ++j)
      b[j] = *(const short8v*)&Bs[wc * WN + j * 16 + lr][lk];
    #pragma unroll
    for (int i = 0; i < 2; ++i)
      #pragma unroll
      for (int j = 0; j < NF; ++j)
        acc[i][j] = __builtin_amdgcn_mfma_f32_16x16x32_bf16(a[i], b[j], acc[i][j], 0, 0, 0);
    __syncthreads();
    if (kt + 1 < nk) STOREL();
    __syncthreads();
  }
#undef LOADG
#undef STOREL

  #pragma unroll
  for (int i = 0; i < 2; ++i)
    #pragma unroll
    for (int j = 0; j < NF; ++j) {
      int gc = n0 + wc * WN + j * 16 + (lane & 15);
      float bv = HAS_BIAS ? bias[gc] : 0.f;
      #pragma unroll
      for (int r = 0; r < 4; ++r) {
        int gr = m0 + wr * 32 + i * 16 + (lane >> 4) * 4 + r;
        float v = acc[i][j][r] + bv;
        if (BF16_OUT) ((short*)Cp)[(size_t)gr * ldc + gc] = bfr(v);
        else          ((float*)Cp)[(size_t)gr * ldc + gc] = v;
      }
    }
}

// ---- FUSED gates GEMM + LSTM cell, pipelined BK=64 --------------------------------------
__global__ __launch_bounds__(256) void gates_cell_f(const short* __restrict__ A2cur,
                                                    short* __restrict__ A2nxt,
                                                    const short* __restrict__ W1p,
                                                    const float* __restrict__ embW,
                                                    const int* __restrict__ seq,
                                                    const int* __restrict__ lens,
                                                    float* __restrict__ C,
                                                    float* __restrict__ Hst,
                                                    short* __restrict__ hcatbf,
                                                    float* __restrict__ outp, int t) {
  union SMem {
    struct { short A[64][72]; short B[128][72]; } s;
    float acc[64][132];
  };
  __shared__ __align__(16) SMem sm;
  const int tid = threadIdx.x;
  const int lane = tid & 63, wave = tid >> 6;
  const int wr = wave >> 1, wc = wave & 1;
  const int bid = blockIdx.x;
  const int col = ((bid & 7) << 1) | ((bid >> 3) & 1);   // XCD stripe
  const int row = bid >> 4;
  const int m0 = row * 64, n0 = col * 128;
  f32x4 acc[2][4];
  #pragma unroll
  for (int i = 0; i < 2; ++i)
    #pragma unroll
    for (int j = 0; j < 4; ++j) acc[i][j] = (f32x4){0.f, 0.f, 0.f, 0.f};

  const int ar0 = tid >> 3, sc0 = (tid & 7) * 8;
  const int lr = lane & 15, lk = (lane >> 4) * 8;
  uint4 pa[2], pb[4];

#define GLOAD(KT)                                                                   \
  {                                                                                 \
    _Pragma("unroll")                                                               \
    for (int q = 0; q < 2; ++q)                                                     \
      pa[q] = *(const uint4*)&A2cur[(size_t)(m0 + ar0 + q * 32) * KA2 + (KT) * 64 + sc0]; \
    _Pragma("unroll")                                                               \
    for (int q = 0; q < 4; ++q)                                                     \
      pb[q] = *(const uint4*)&W1p[(size_t)(n0 + ar0 + q * 32) * KA2 + (KT) * 64 + sc0];   \
  }
#define GSTORE()                                                                    \
  {                                                                                 \
    _Pragma("unroll")                                                               \
    for (int q = 0; q < 2; ++q) *(uint4*)&sm.s.A[ar0 + q * 32][sc0] = pa[q];        \
    _Pragma("unroll")                                                               \
    for (int q = 0; q < 4; ++q) *(uint4*)&sm.s.B[ar0 + q * 32][sc0] = pb[q];        \
  }

  GLOAD(0);
  GSTORE();
  __syncthreads();
  for (int kt = 0; kt < 16; ++kt) {
    if (kt + 1 < 16) GLOAD(kt + 1);
    short8v a[2][2], b[4][2];
    #pragma unroll
    for (int i = 0; i < 2; ++i)
      #pragma unroll
      for (int kk = 0; kk < 2; ++kk)
        a[i][kk] = *(const short8v*)&sm.s.A[wr * 32 + i * 16 + lr][kk * 32 + lk];
    #pragma unroll
    for (int j = 0; j < 4; ++j)
      #pragma unroll
      for (int kk = 0; kk < 2; ++kk)
        b[j][kk] = *(const short8v*)&sm.s.B[wc * 64 + j * 16 + lr][kk * 32 + lk];
    #pragma unroll
    for (int kk = 0; kk < 2; ++kk)
      #pragma unroll
      for (int i = 0; i < 2; ++i)
        #pragma unroll
        for (int j = 0; j < 4; ++j)
          acc[i][j] = __builtin_amdgcn_mfma_f32_16x16x32_bf16(a[i][kk], b[j][kk],
                                                              acc[i][j], 0, 0, 0);
    __syncthreads();
    if (kt + 1 < 16) GSTORE();
    __syncthreads();
  }
#undef GLOAD
#undef GSTORE

  // stage accumulators to LDS (overlays A/B — past the double barrier)
  #pragma unroll
  for (int i = 0; i < 2; ++i)
    #pragma unroll
    for (int j = 0; j < 4; ++j)
      #pragma unroll
      for (int r = 0; r < 4; ++r)
        sm.acc[wr * 32 + i * 16 + (lane >> 4) * 4 + r][wc * 64 + j * 16 + (lane & 15)] =
            acc[i][j][r];
  __syncthreads();

  // fused LSTM cell
  const int bl = tid >> 2;
  const int gb = m0 + bl;
  const int ju0 = (tid & 3) * 8;
  const int tok = seq[gb * SL + t];
  const bool am = t < lens[gb];
  const float* ewr = embW + (size_t)tok * NG + n0;
  #pragma unroll
  for (int u = 0; u < 8; ++u) {
    int jl = ju0 + u;
    int jg = (n0 >> 2) + jl;
    f32x4 ew = *(const f32x4*)&ewr[jl * 4];
    f32x4 g4 = *(const f32x4*)&sm.acc[bl][jl * 4];
    float gi = g4.x + ew.x, gf = g4.y + ew.y, gg = g4.z + ew.z, go = g4.w + ew.w;
    size_t cix = (size_t)gb * 512 + jg;
    float co = C[cix];
    float cn = sigmf(gf) * co + sigmf(gi) * tanhf(gg);
    float hn = sigmf(go) * tanhf(cn);
    hcatbf[(size_t)gb * 1024 + jg] = bfr(hn);
    hcatbf[(size_t)gb * 1024 + 512 + jg] = bfr(cn);
    short hv;
    if (am) { C[cix] = cn; Hst[cix] = hn; hv = bfr(hn); }
    else hv = A2cur[(size_t)gb * KA2 + 512 + jg];
    A2nxt[(size_t)gb * KA2 + 512 + jg] = hv;
    outp[((size_t)gb * SL + t) * 512 + jg] = am ? hn : 0.0f;
  }
}

// ---- attention: parallel scores (4 lanes/row) + softmax + ctx ---------------------------
template <bool ABF>
__global__ __launch_bounds__(256) void attn_row(const float* __restrict__ dec,
                                                const unsigned short* __restrict__ ef,
                                                const void* __restrict__ attnp,
                                                const float* __restrict__ mask,
                                                const int* __restrict__ lens,
                                                const short* __restrict__ A2cur,
                                                short* __restrict__ A2nxt,
                                                const float* __restrict__ v, int t) {
  __shared__ float sdec[HIDN], sv[HIDN], sa[SL], sraw[SL];
  const int b = blockIdx.x, tid = threadIdx.x;
  for (int k = tid; k < HIDN; k += 256) {
    sdec[k] = dec[(size_t)b * HIDN + k];
    sv[k] = v[k];
  }
  __syncthreads();
  if (tid < 192) {
    int tt = tid >> 2, q = tid & 3;
    const unsigned short* er = ef + ((size_t)b * SL + tt) * HIDN + q * 128;
    float s = 0.f;
    for (int k8 = 0; k8 < 128; k8 += 8) {
      uint4 u = *(const uint4*)&er[k8];
      const unsigned short* e8 = (const unsigned short*)&u;
      #pragma unroll
      for (int i = 0; i < 8; ++i) {
        int k = q * 128 + k8 + i;
        s += sv[k] * tanhf(bf2f(e8[i]) + sdec[k]);
      }
    }
    s += __shfl_xor(s, 1);
    s += __shfl_xor(s, 2);
    if (q == 0) sraw[tt] = s;
  }
  __syncthreads();
  if (tid < 64) {
    float s = (tid < SL) ? sraw[tid] : -1e30f;
    float mx = s;
    #pragma unroll
    for (int off = 32; off >= 1; off >>= 1) mx = fmaxf(mx, __shfl_xor(mx, off, 64));
    float e = (tid < SL) ? expf(s - mx) * mask[b * SL + tid] : 0.f;
    float sum = e;
    #pragma unroll
    for (int off = 32; off >= 1; off >>= 1) sum += __shfl_xor(sum, off, 64);
    if (tid < SL) sa[tid] = e / sum;
  }
  __syncthreads();
  const bool am = t < lens[b];
  for (int j = tid; j < HIDN; j += 256) {
    short cv;
    if (am) {
      float cx = 0.f;
      #pragma unroll
      for (int tt = 0; tt < SL; ++tt) {
        size_t ai = ((size_t)b * SL + tt) * HIDN + j;
        float av = ABF ? bf2f(((const unsigned short*)attnp)[ai])
                       : ((const float*)attnp)[ai];
        cx += sa[tt] * av;
      }
      cv = bfr(cx);
    } else {
      cv = A2cur[(size_t)b * KA2 + j];
    }
    A2nxt[(size_t)b * KA2 + j] = cv;
  }
}

// ---- final h, c --------------------------------------------------------------------------
__global__ __launch_bounds__(256) void fin2(const float* __restrict__ Hst,
                                            const float* __restrict__ C,
                                            float* __restrict__ outp) {
  int idx = blockIdx.x * 256 + threadIdx.x;
  outp[HPOS + idx] = Hst[idx];
  outp[CPOS + idx] = C[idx];
}

extern "C" void kernel_launch(void* const* d_in, const int* in_sizes, int n_in,
                              void* d_out, int out_size, void* d_ws, size_t ws_size,
                              hipStream_t stream) {
  (void)in_sizes; (void)n_in; (void)out_size;
  const int*   seq  = (const int*)d_in[0];
  const int*   lens = (const int*)d_in[1];
  const float* h0   = (const float*)d_in[2];
  const float* c0   = (const float*)d_in[3];
  const float* attn = (const float*)d_in[4];
  const float* mask = (const float*)d_in[5];
  const float* emb  = (const float*)d_in[6];
  const float* W_ih = (const float*)d_in[7];
  const float* W_hh = (const float*)d_in[8];
  const float* b_ih = (const float*)d_in[9];
  const float* b_hh = (const float*)d_in[10];
  const float* Wh   = (const float*)d_in[11];
  const float* Wdp  = (const float*)d_in[12];
  const float* bdp  = (const float*)d_in[13];
  const float* vv   = (const float*)d_in[14];
  float* outp = (float*)d_out;

  float* ws = (float*)d_ws;
  short* W1p    = (short*)(ws);                    // [0, 1048576)
  short* Wdpb   = (short*)(ws + 1048576);          // [1048576, 1310720)
  short* Whb    = (short*)(ws + 1310720);          // [1310720, 1441792)
  short* Wxpb   = (short*)(ws + 1441792);          // [1441792, 1572864)
  short* embbf  = (short*)(ws + 1572864);          // [1572864, 1613824)
  float* bperm  = ws + 1613824;                    // [1613824, 1615872)
  float* embW   = ws + 1615872;                    // 640*2048 -> [1615872, 2926592)
  unsigned short* ef = (unsigned short*)(ws + 2926592);  // [2926592, 15509504)
  short* A2b[2] = { (short*)(ws + 15509504), (short*)(ws + 16033792) };
  short* hcatbf = (short*)(ws + 16558080);
  float* Hst    = ws + 17082368;
  float* C      = ws + 17606656;
  float* dec    = ws + 18130944;                   // end 18655232 f = 74.6 MB
  short* attnbf = (short*)(ws + 18655232);         // optional, end 124.95 MB
  const bool useabf = ws_size >= (size_t)31238144 * 4;

  prep_w1p<<<(NG * KA2 + 255) / 256, 256, 0, stream>>>(W_ih, W_hh, W1p);
  prep_wxp<<<(NG * EMBD + 255) / 256, 256, 0, stream>>>(W_ih, b_ih, b_hh, Wxpb, bperm);
  prep_embb<<<(640 * EMBD + 255) / 256, 256, 0, stream>>>(emb, embbf);
  prep_bf<<<(512 * 1024 + 255) / 256, 256, 0, stream>>>(Wdp, Wdpb, 512 * 1024);
  prep_bf<<<(512 * 512 + 255) / 256, 256, 0, stream>>>(Wh, Whb, 512 * 512);
  if (useabf)
    prep_bf<<<(25165824 + 255) / 256, 256, 0, stream>>>(attn, attnbf, 25165824);
  // embW = embbf @ Wxpb^T + bperm  (640 x 2048, K=128)
  gemm_mfma<128, false, false, true><<<dim3(NG / 128, 640 / 64), 256, 0, stream>>>(
      embbf, EMBD, Wxpb, EMBD, bperm, embW, NG, EMBD);
  // ef = attn @ Wh^T  (49152 x 512, K=512), bf16 out, BN=256 (2 col-passes over A)
  gemm_mfma<256, true, true, false><<<dim3(512 / 256, (NB * SL) / 64), 256, 0, stream>>>(
      attn, HIDN, Whb, HIDN, nullptr, ef, HIDN, HIDN);
  init2<<<(NB * HIDN) / 256, 256, 0, stream>>>(h0, c0, A2b[0], Hst, C);

  for (int t = 0; t < SL; ++t) {
    int cur = t & 1, nxt = cur ^ 1;
    gates_cell_f<<<256, 256, 0, stream>>>(A2b[cur], A2b[nxt], W1p, embW, seq, lens,
                                          C, Hst, hcatbf, outp, t);
    // dec = hcatbf @ Wdpb^T + bdp  (1024 x 512, K=1024)
    gemm_mfma<64, false, false, true><<<dim3(HIDN / 64, NB / 64), 256, 0, stream>>>(
        hcatbf, 1024, Wdpb, 1024, bdp, dec, HIDN, 1024);
    if (useabf)
      attn_row<true><<<NB, 256, 0, stream>>>(dec, ef, attnbf, mask, lens,
                                             A2b[cur], A2b[nxt], vv, t);
    else
      attn_row<false><<<NB, 256, 0, stream>>>(dec, ef, attn, mask, lens,
                                              A2b[cur], A2b[nxt], vv, t);
  }
  fin2<<<(NB * HIDN) / 256, 256, 0, stream>>>(Hst, C, outp);
}